// Round 2
// baseline (136.064 us; speedup 1.0000x reference)
//
#include <hip/hip_runtime.h>
#include <math.h>

// RESUS_NN_2327872274812: Q=8192, S=30, D=512.
#define QN 8192
#define SN 30
#define DN 512
#define QT 32            // queries per block
#define BLK 512          // 32 q-slots x 16 d-chunks
#define NC 16            // chunks
#define CHUNK 32         // d per thread
#define ST 10            // support tile (accumulators stay in VGPRs)
#define NT 3             // number of s-tiles
#define PSTRIDE 25       // part row stride: 20 payload + 5 pad; gcd(25,32)=1 -> conflict-free

__global__ __launch_bounds__(BLK, 2)
void resus_fused(const float* __restrict__ query,      // [Q][D]
                 const float* __restrict__ support,    // [S][D]
                 const float* __restrict__ support_y,  // [S]
                 const float* __restrict__ support_pr, // [S]
                 const float* __restrict__ query_pr,   // [Q]
                 const float* __restrict__ fc1_w,      // [D]
                 const float* __restrict__ adj_scale,  // [30]
                 const float* __restrict__ adj_bias,   // [30]
                 const int*   __restrict__ num_samples,// [1]
                 float* __restrict__ out)              // [2*Q]
{
    __shared__ float sv[SN * DN];          // 61440 B, support row-major
    __shared__ float part[QT * PSTRIDE];   // 3200 B per-tile partials
    __shared__ float dy[SN];               // 120 B

    const int tid = threadIdx.x;
    const int ql  = tid & (QT - 1);        // query slot 0..31
    const int c   = tid >> 5;              // d-chunk 0..15 (2 per wave)
    const int q   = blockIdx.x * QT + ql;

    // ---- registers: this thread's query chunk + w chunk (held all kernel) ----
    float4 qv[CHUNK / 4];
    float4 wv[CHUNK / 4];
    {
        const float* qrow = query + q * DN + c * CHUNK;
        const float* wrow = fc1_w + c * CHUNK;
#pragma unroll
        for (int g = 0; g < CHUNK / 4; ++g) {
            qv[g] = *reinterpret_cast<const float4*>(qrow + 4 * g);
            wv[g] = *reinterpret_cast<const float4*>(wrow + 4 * g);
        }
    }

    // ---- stage support into LDS (coalesced float4) + delta_y ----
    {
        float4* sv4 = reinterpret_cast<float4*>(sv);
        const float4* sg = reinterpret_cast<const float4*>(support);
        for (int i = tid; i < SN * DN / 4; i += BLK) sv4[i] = sg[i];
    }
    if (tid < SN)
        dy[tid] = support_y[tid] - 1.0f / (1.0f + expf(-support_pr[tid]));

    // online-softmax running state (only tid<QT uses it)
    float run_m = -1e30f, run_den = 0.0f, run_num = 0.0f, run_l2 = 0.0f;

    for (int t = 0; t < NT; ++t) {
        // zero this tile's partial array
        __syncthreads();               // epilogue of prev tile done / staging done
        for (int i = tid; i < QT * PSTRIDE; i += BLK) part[i] = 0.0f;
        __syncthreads();

        float sc[ST], sq[ST];
#pragma unroll
        for (int s = 0; s < ST; ++s) { sc[s] = 0.0f; sq[s] = 0.0f; }

        const float* sbase = sv + (t * ST) * DN + c * CHUNK;
#pragma unroll
        for (int g = 0; g < CHUNK / 4; ++g) {
            const float4 qg = qv[g];
            const float4 wg = wv[g];
            const float* sp = sbase + 4 * g;
#pragma unroll
            for (int s = 0; s < ST; ++s) {
                const float4 s4 = *reinterpret_cast<const float4*>(sp + s * DN);
                float d0 = qg.x - s4.x;
                float d1 = qg.y - s4.y;
                float d2 = qg.z - s4.z;
                float d3 = qg.w - s4.w;
                sc[s] = fmaf(wg.x, fabsf(d0), sc[s]);
                sc[s] = fmaf(wg.y, fabsf(d1), sc[s]);
                sc[s] = fmaf(wg.z, fabsf(d2), sc[s]);
                sc[s] = fmaf(wg.w, fabsf(d3), sc[s]);
                sq[s] = fmaf(d0, d0, sq[s]);
                sq[s] = fmaf(d1, d1, sq[s]);
                sq[s] = fmaf(d2, d2, sq[s]);
                sq[s] = fmaf(d3, d3, sq[s]);
            }
        }

        // combine the 16 d-chunk partials per query
        float* prow = part + ql * PSTRIDE;
#pragma unroll
        for (int s = 0; s < ST; ++s) {
            atomicAdd(&prow[s], sc[s]);
            atomicAdd(&prow[ST + s], sq[s]);
        }
        __syncthreads();

        // online-softmax update for this tile (one thread per query)
        if (tid < QT) {
            const float* r = part + tid * PSTRIDE;
#pragma unroll
            for (int s = 0; s < ST; ++s) {
                float x = r[s];
                float m_new = fmaxf(run_m, x);
                float scale = expf(run_m - m_new);
                float e     = expf(x - m_new);
                run_den = run_den * scale + e;
                run_num = fmaf(dy[t * ST + s], e, run_num * scale);
                run_m   = m_new;
                run_l2 += sqrtf(r[ST + s]);
            }
        }
    }
    __syncthreads();

    // ---- final write ----
    if (tid < QT) {
        const int qg = blockIdx.x * QT + tid;
        const int ns = num_samples[0];
        const float scale = fabsf(adj_scale[ns - 1]);
        const float bias  = adj_bias[ns - 1];
        out[qg]      = run_num / run_den * scale + bias + query_pr[qg];
        out[QN + qg] = run_l2 * (1.0f / (float)SN);
    }
}

extern "C" void kernel_launch(void* const* d_in, const int* in_sizes, int n_in,
                              void* d_out, int out_size, void* d_ws, size_t ws_size,
                              hipStream_t stream)
{
    const float* query      = (const float*)d_in[0];
    const float* support    = (const float*)d_in[1];
    const float* support_y  = (const float*)d_in[2];
    const float* support_pr = (const float*)d_in[3];
    const float* query_pr   = (const float*)d_in[4];
    const float* fc1_w      = (const float*)d_in[5];
    // d_in[6] = fc1_b: cancels in softmax, unused
    const float* adj_scale  = (const float*)d_in[7];
    const float* adj_bias   = (const float*)d_in[8];
    const int*   num_s      = (const int*)d_in[9];
    float* out = (float*)d_out;

    dim3 grid(QN / QT);   // 256 blocks, 1 per CU
    dim3 block(BLK);      // 8 waves
    hipLaunchKernelGGL(resus_fused, grid, block, 0, stream,
                       query, support, support_y, support_pr, query_pr,
                       fc1_w, adj_scale, adj_bias, num_s, out);
}